// Round 11
// baseline (240.820 us; speedup 1.0000x reference)
//
#include <hip/hip_runtime.h>

typedef unsigned short ushort_t;
typedef __attribute__((ext_vector_type(8)))  short  short8;
typedef __attribute__((ext_vector_type(4)))  float  float4v;
typedef __attribute__((ext_vector_type(4)))  int    int4v;

#define N_NODES 4096
#define NHEADS  4
#define DK      128
#define ODIM    512
#define KDIM    512

__device__ __forceinline__ float bf2f(ushort_t u) {
    return __uint_as_float(((unsigned)u) << 16);
}
__device__ __forceinline__ ushort_t f2bf_rne(float f) {
    unsigned u = __float_as_uint(f);
    u += 0x7fffu + ((u >> 16) & 1u);
    return (ushort_t)(u >> 16);
}

// ---------------------------------------------------------------------------
// Kernel 1: bit-pack mask = (A != 0) || (i == j); block 0 wave 0 also runs the
// input-dtype detector (1 = fp32 inputs).
// ---------------------------------------------------------------------------
__global__ __launch_bounds__(256) void pack_mask_k(const int* __restrict__ A,
                                                   unsigned long long* __restrict__ P,
                                                   const ushort_t* __restrict__ Hraw,
                                                   int* __restrict__ flag)
{
    if (blockIdx.x == 0 && threadIdx.x < 64) {
        const int lane = threadIdx.x;
        int cnt = 0;
        #pragma unroll
        for (int s = 0; s < 16; ++s) {
            ushort_t v = Hraw[(lane * 16 + s) * 2];
            int e = (v >> 7) & 0xFF;
            cnt += (((e >= 90) && (e <= 140)) || (v == 0)) ? 1 : 0;
        }
        #pragma unroll
        for (int off = 32; off; off >>= 1) cnt += __shfl_down(cnt, off);
        if (lane == 0) *flag = (cnt < 768) ? 1 : 0;
    }
    #pragma unroll
    for (int k = 0; k < 4; ++k) {
        int flat = (k * 16384 + blockIdx.x) * 256 + threadIdx.x;
        int row  = flat >> 12;
        int col  = flat & 4095;
        int a    = A[flat];
        unsigned long long m = __ballot((a != 0) || (row == col));
        if ((threadIdx.x & 63) == 0) P[flat >> 6] = m;
    }
}

// ---------------------------------------------------------------------------
// Kernel 2: WT[n][k] = W[k][n] as bf16 (dual-dtype input).
// ---------------------------------------------------------------------------
__global__ __launch_bounds__(256) void transpose_w_k(const void* __restrict__ W,
                                                     ushort_t* __restrict__ WT,
                                                     const int* __restrict__ flag)
{
    __shared__ ushort_t lt[64][72];
    const int f32 = *flag;
    const int tid = threadIdx.x;
    const int ti = blockIdx.x >> 3, tj = blockIdx.x & 7;
    const int r = tid >> 2, c2 = tid & 3;
    const size_t eo = (size_t)(ti * 64 + r) * KDIM + tj * 64 + c2 * 16;
    if (f32) {
        const float4v* src = (const float4v*)((const float*)W + eo);
        float4v f0 = src[0], f1 = src[1], f2 = src[2], f3 = src[3];
        #pragma unroll
        for (int e = 0; e < 4; ++e) {
            lt[r][c2 * 16 +  0 + e] = f2bf_rne(f0[e]);
            lt[r][c2 * 16 +  4 + e] = f2bf_rne(f1[e]);
            lt[r][c2 * 16 +  8 + e] = f2bf_rne(f2[e]);
            lt[r][c2 * 16 + 12 + e] = f2bf_rne(f3[e]);
        }
    } else {
        const short8* src = (const short8*)((const ushort_t*)W + eo);
        short8 v0 = src[0];
        short8 v1 = src[1];
        *(short8*)&lt[r][c2 * 16]     = v0;
        *(short8*)&lt[r][c2 * 16 + 8] = v1;
    }
    __syncthreads();
    #pragma unroll
    for (int itr = 0; itr < 2; ++itr) {
        int idx = itr * 256 + tid;
        int n = idx >> 3, c = idx & 7;
        short8 vv;
        #pragma unroll
        for (int e = 0; e < 8; ++e) vv[e] = (short)lt[c * 8 + e][n];
        *(short8*)(WT + (size_t)(tj * 64 + n) * KDIM + ti * 64 + c * 8) = vv;
    }
}

// ---------------------------------------------------------------------------
// Kernel 3: WhT[n][i] = (H @ W)[i][n].  16x16x32 MFMA, dual-dtype A loads.
// ---------------------------------------------------------------------------
__global__ __launch_bounds__(256) void gemm_wht_dual_k(const void* __restrict__ H,
                                                       const ushort_t* __restrict__ WT,
                                                       ushort_t* __restrict__ WhT,
                                                       const int* __restrict__ flag)
{
    __shared__ ushort_t lt[64][72];
    const int f32 = *flag;
    const int tid  = threadIdx.x;
    const int lane = tid & 63;
    const int wid  = tid >> 6;
    const int quad = lane >> 4;
    const int l15  = lane & 15;
    const int bm = blockIdx.x >> 3, bn = blockIdx.x & 7;
    const int i0 = bm * 64, n0 = bn * 64;

    const size_t aoff = (size_t)(i0 + wid * 16 + l15) * KDIM + quad * 8;
    const short8* bp0 = (const short8*)(WT + (size_t)(n0 +  0 + l15) * KDIM) + quad;
    const short8* bp1 = (const short8*)(WT + (size_t)(n0 + 16 + l15) * KDIM) + quad;
    const short8* bp2 = (const short8*)(WT + (size_t)(n0 + 32 + l15) * KDIM) + quad;
    const short8* bp3 = (const short8*)(WT + (size_t)(n0 + 48 + l15) * KDIM) + quad;

    float4v acc0, acc1, acc2, acc3;
    #pragma unroll
    for (int e = 0; e < 4; ++e) { acc0[e] = 0.f; acc1[e] = 0.f; acc2[e] = 0.f; acc3[e] = 0.f; }

    #pragma unroll 4
    for (int k8 = 0; k8 < 64; k8 += 4) {
        short8 a;
        if (f32) {
            const float4v* fp = (const float4v*)((const float*)H + aoff + (size_t)k8 * 8);
            float4v x0 = fp[0], x1 = fp[1];
            #pragma unroll
            for (int e = 0; e < 4; ++e) {
                a[e]     = (short)f2bf_rne(x0[e]);
                a[4 + e] = (short)f2bf_rne(x1[e]);
            }
        } else {
            a = *(const short8*)((const ushort_t*)H + aoff + (size_t)k8 * 8);
        }
        acc0 = __builtin_amdgcn_mfma_f32_16x16x32_bf16(a, bp0[k8], acc0, 0, 0, 0);
        acc1 = __builtin_amdgcn_mfma_f32_16x16x32_bf16(a, bp1[k8], acc1, 0, 0, 0);
        acc2 = __builtin_amdgcn_mfma_f32_16x16x32_bf16(a, bp2[k8], acc2, 0, 0, 0);
        acc3 = __builtin_amdgcn_mfma_f32_16x16x32_bf16(a, bp3[k8], acc3, 0, 0, 0);
    }

    #pragma unroll
    for (int r = 0; r < 4; ++r) {
        int m = wid * 16 + quad * 4 + r;
        lt[ 0 + l15][m] = f2bf_rne(acc0[r]);
        lt[16 + l15][m] = f2bf_rne(acc1[r]);
        lt[32 + l15][m] = f2bf_rne(acc2[r]);
        lt[48 + l15][m] = f2bf_rne(acc3[r]);
    }
    __syncthreads();
    #pragma unroll
    for (int itr = 0; itr < 2; ++itr) {
        int idx = itr * 256 + tid;
        int n = idx >> 3, c = idx & 7;
        short8 v = *(const short8*)&lt[n][c * 8];
        *(short8*)(WhT + (size_t)(n0 + n) * N_NODES + i0 + c * 8) = v;
    }
}

// ---------------------------------------------------------------------------
// Kernel 4: sl[h][i], sr[h][i] from WhT (bf16) and a_l/a_r (dual-dtype).
// ---------------------------------------------------------------------------
__global__ __launch_bounds__(256) void slsr_k(const ushort_t* __restrict__ WhT,
                                              const void* __restrict__ al,
                                              const void* __restrict__ ar,
                                              float* __restrict__ sl,
                                              float* __restrict__ sr,
                                              const int* __restrict__ flag)
{
    const int f32 = *flag;
    const int b = blockIdx.x;
    const int h = b >> 4;
    const int i = ((b & 15) << 8) + threadIdx.x;
    float asl = 0.f, asr = 0.f;
    #pragma unroll 8
    for (int d = 0; d < DK; ++d) {
        float v  = bf2f(WhT[(size_t)(h * DK + d) * N_NODES + i]);
        float av = f32 ? ((const float*)al)[h * DK + d] : bf2f(((const ushort_t*)al)[h * DK + d]);
        float bv = f32 ? ((const float*)ar)[h * DK + d] : bf2f(((const ushort_t*)ar)[h * DK + d]);
        asl += v * av;
        asr += v * bv;
    }
    sl[h * N_NODES + i] = asl;
    sr[h * N_NODES + i] = asr;
}

// ---------------------------------------------------------------------------
// Kernel 5 v9: attention, direct global->VGPR V loads PINNED EARLY with
// __builtin_amdgcn_sched_barrier(0) (compiler cannot sink them past the
// softmax, so softmax's ~300 cyc covers the L2 latency and the LDS round
// trip is gone).  Grid 512 = (128 i-tiles x 4 heads); 256 thr / 4 waves;
// wave = j-quarter (1024 j, 16 windows of 64).  MFMA-ones denominator.
// LDS only 32 KB (srs + mask; epilogue overlays) -> occupancy set by VGPR.
// ---------------------------------------------------------------------------
__global__ __launch_bounds__(256) void attn_k(const ushort_t* __restrict__ WhT,
                                              const unsigned* __restrict__ Apack,
                                              const float* __restrict__ sl,
                                              const float* __restrict__ sr,
                                              void* __restrict__ out,
                                              const int* __restrict__ flag)
{
    __shared__ char smem[32768] __attribute__((aligned(16)));
    float*    srs  = (float*)smem;                       // 4096 f32, 16 KB
    unsigned (*mbuf)[128] = (unsigned (*)[128])(smem + 16384); // 32x128, 16 KB

    const int f32  = *flag;
    const int tid  = threadIdx.x;
    const int lane = tid & 63;
    const int wq   = tid >> 6;               // j-quarter 0..3
    const int quad = lane >> 4;
    const int l15  = lane & 15;
    const int h    = blockIdx.x & 3;
    const int i0   = (blockIdx.x >> 2) << 5; // 32-row tile

    for (int j = tid; j < N_NODES; j += 256) srs[j] = sr[h * N_NODES + j];
    for (int t = tid; t < 32 * 128; t += 256) {
        int r = t >> 7, c = t & 127;
        mbuf[r][c] = Apack[(size_t)(i0 + r) * 128 + c];
    }
    const float slv0 = sl[h * N_NODES + i0 + l15];
    const float slv1 = sl[h * N_NODES + i0 + 16 + l15];
    __syncthreads();

    const float C1 = 1.44269504f;             // log2(e)
    const float C2 = 0.2f * 1.44269504f;

    float4v acc[2][8];
    #pragma unroll
    for (int mg = 0; mg < 2; ++mg)
        #pragma unroll
        for (int nt = 0; nt < 8; ++nt)
            #pragma unroll
            for (int e = 0; e < 4; ++e) acc[mg][nt][e] = 0.f;
    float4v accden0, accden1;
    #pragma unroll
    for (int e = 0; e < 4; ++e) { accden0[e] = 0.f; accden1[e] = 0.f; }

    short8 ones;
    #pragma unroll
    for (int e = 0; e < 8; ++e) ones[e] = (short)0x3F80;   // bf16 1.0

    // B-frag: lane holds V^T[d = nt*16 + l15][j = j0 + kseg*32 + quad*8 ..+7]
    const ushort_t* vb = WhT + (size_t)(h * DK + l15) * N_NODES + wq * 1024 + quad * 8;

    #pragma unroll 1
    for (int it = 0; it < 16; ++it) {
        const int jl = it * 64;
        const int j0 = wq * 1024 + jl;
        const int mc = j0 >> 5;

        // ---- V loads issued FIRST, pinned above softmax by the fence ----
        short8 bf[8][2];
        #pragma unroll
        for (int nt = 0; nt < 8; ++nt) {
            bf[nt][0] = *(const short8*)(vb + (size_t)nt * 16 * N_NODES + jl);
            bf[nt][1] = *(const short8*)(vb + (size_t)nt * 16 * N_NODES + jl + 32);
        }
        __builtin_amdgcn_sched_barrier(0);    // nothing crosses: loads stay early

        const unsigned wa0 = mbuf[l15][mc],      wa1 = mbuf[l15][mc + 1];
        const unsigned wb0 = mbuf[16 + l15][mc], wb1 = mbuf[16 + l15][mc + 1];

        short8 pf0[2], pf1[2];
        #pragma unroll
        for (int s = 0; s < 2; ++s) {
            const float* sp = &srs[j0 + s * 32 + quad * 8];
            const float4v s0 = *(const float4v*)sp;
            const float4v s1 = *(const float4v*)(sp + 4);
            const unsigned wa = s ? wa1 : wa0;
            const unsigned wb = s ? wb1 : wb0;
            float p0[8], p1[8];
            #pragma unroll
            for (int jj = 0; jj < 8; ++jj) {
                float srj = (jj < 4) ? s0[jj] : s1[jj - 4];
                int bit = quad * 8 + jj;
                float x0 = slv0 + srj;
                float t0 = fmaxf(x0 * C1, x0 * C2);
                t0 = ((wa >> bit) & 1u) ? t0 : -1e30f;
                p0[jj] = __builtin_amdgcn_exp2f(t0);
                float x1 = slv1 + srj;
                float t1 = fmaxf(x1 * C1, x1 * C2);
                t1 = ((wb >> bit) & 1u) ? t1 : -1e30f;
                p1[jj] = __builtin_amdgcn_exp2f(t1);
            }
            int4v iv0, iv1;
            #pragma unroll
            for (int q2 = 0; q2 < 4; ++q2) {
                iv0[q2] = (int)__builtin_amdgcn_perm(__float_as_uint(p0[2 * q2 + 1]),
                                                     __float_as_uint(p0[2 * q2]), 0x07060302u);
                iv1[q2] = (int)__builtin_amdgcn_perm(__float_as_uint(p1[2 * q2 + 1]),
                                                     __float_as_uint(p1[2 * q2]), 0x07060302u);
            }
            pf0[s] = __builtin_bit_cast(short8, iv0);
            pf1[s] = __builtin_bit_cast(short8, iv1);
        }

        #pragma unroll
        for (int nt = 0; nt < 8; ++nt) {
            acc[0][nt] = __builtin_amdgcn_mfma_f32_16x16x32_bf16(pf0[0], bf[nt][0], acc[0][nt], 0, 0, 0);
            acc[0][nt] = __builtin_amdgcn_mfma_f32_16x16x32_bf16(pf0[1], bf[nt][1], acc[0][nt], 0, 0, 0);
            acc[1][nt] = __builtin_amdgcn_mfma_f32_16x16x32_bf16(pf1[0], bf[nt][0], acc[1][nt], 0, 0, 0);
            acc[1][nt] = __builtin_amdgcn_mfma_f32_16x16x32_bf16(pf1[1], bf[nt][1], acc[1][nt], 0, 0, 0);
        }
        accden0 = __builtin_amdgcn_mfma_f32_16x16x32_bf16(pf0[0], ones, accden0, 0, 0, 0);
        accden0 = __builtin_amdgcn_mfma_f32_16x16x32_bf16(pf0[1], ones, accden0, 0, 0, 0);
        accden1 = __builtin_amdgcn_mfma_f32_16x16x32_bf16(pf1[0], ones, accden1, 0, 0, 0);
        accden1 = __builtin_amdgcn_mfma_f32_16x16x32_bf16(pf1[1], ones, accden1, 0, 0, 0);
    }

    // ---- epilogue: overlay red/lsum on dead srs/mbuf ----
    float* red  = (float*)smem;               // 32 x 128 fp32, 16 KB
    float* lsum = (float*)(smem + 16384);     // 4 x 32 fp32
    __syncthreads();                          // all waves out of the main loop

    if (l15 == 0) {
        #pragma unroll
        for (int r = 0; r < 4; ++r) {
            lsum[wq * 32 + quad * 4 + r]      = accden0[r];
            lsum[wq * 32 + 16 + quad * 4 + r] = accden1[r];
        }
    }
    #define RED_WRITE                                                                \
        { _Pragma("unroll")                                                          \
          for (int mg = 0; mg < 2; ++mg)                                             \
            _Pragma("unroll")                                                        \
            for (int nt = 0; nt < 8; ++nt)                                           \
              _Pragma("unroll")                                                      \
              for (int r = 0; r < 4; ++r)                                            \
                red[(mg * 16 + quad * 4 + r) * 128 + nt * 16 + l15] = acc[mg][nt][r]; }
    #define RED_ADD                                                                 \
        { _Pragma("unroll")                                                          \
          for (int mg = 0; mg < 2; ++mg)                                             \
            _Pragma("unroll")                                                        \
            for (int nt = 0; nt < 8; ++nt)                                           \
              _Pragma("unroll")                                                      \
              for (int r = 0; r < 4; ++r)                                            \
                acc[mg][nt][r] += red[(mg * 16 + quad * 4 + r) * 128 + nt * 16 + l15]; }

    if (wq == 1) RED_WRITE
    __syncthreads();
    if (wq == 0) RED_ADD
    __syncthreads();
    if (wq == 3) RED_WRITE
    __syncthreads();
    if (wq == 2) RED_ADD
    __syncthreads();
    if (wq == 2) RED_WRITE
    __syncthreads();
    if (wq == 0) {
        RED_ADD
        #pragma unroll
        for (int mg = 0; mg < 2; ++mg) {
            float linv[4];
            #pragma unroll
            for (int r = 0; r < 4; ++r) {
                int rowi = mg * 16 + quad * 4 + r;
                float den = lsum[rowi] + lsum[32 + rowi] + lsum[64 + rowi] + lsum[96 + rowi];
                linv[r] = 1.0f / fmaxf(den, 1e-37f);
            }
            #pragma unroll
            for (int nt = 0; nt < 8; ++nt)
                #pragma unroll
                for (int r = 0; r < 4; ++r) {
                    int rowi = mg * 16 + quad * 4 + r;
                    float v = acc[mg][nt][r] * linv[r];
                    float e = __builtin_amdgcn_exp2f(v * C1) - 1.0f;
                    float o = (v > 0.f) ? v : e;
                    size_t oidx = (size_t)(i0 + rowi) * ODIM + h * DK + nt * 16 + l15;
                    if (f32) ((float*)out)[oidx] = o;
                    else     ((ushort_t*)out)[oidx] = f2bf_rne(o);
                }
        }
    }
    #undef RED_WRITE
    #undef RED_ADD
}

// ---------------------------------------------------------------------------
extern "C" void kernel_launch(void* const* d_in, const int* in_sizes, int n_in,
                              void* d_out, int out_size, void* d_ws, size_t ws_size,
                              hipStream_t stream)
{
    const void* H  = d_in[0];
    const int*  A  = (const int*)d_in[1];
    const void* W  = d_in[2];
    const void* al = d_in[3];
    const void* ar = d_in[4];

    if (ws_size < (7u << 20)) return;

    char* ws = (char*)d_ws;
    ushort_t* WhT   = (ushort_t*)ws;                                    // 4 MB
    unsigned long long* Apack = (unsigned long long*)(ws + (4u << 20)); // 2 MB
    ushort_t* WT    = (ushort_t*)(ws + (6u << 20));                     // 512 KB
    float*    sl    = (float*)(ws + (6u << 20) + (512u << 10));         // 64 KB
    float*    sr    = (float*)(ws + (6u << 20) + (576u << 10));         // 64 KB
    int*      flag  = (int*)(ws + (6u << 20) + (640u << 10));           // 4 B

    pack_mask_k    <<<16384, 256, 0, stream>>>(A, Apack, (const ushort_t*)H, flag);
    transpose_w_k  <<<64,    256, 0, stream>>>(W, WT, flag);
    gemm_wht_dual_k<<<512,   256, 0, stream>>>(H, WT, WhT, flag);
    slsr_k         <<<64,    256, 0, stream>>>(WhT, al, ar, sl, sr, flag);
    attn_k         <<<512,   256, 0, stream>>>(WhT, (const unsigned*)Apack, sl, sr, (void*)d_out, flag);
}

// Round 12
// 212.021 us; speedup vs baseline: 1.1358x; 1.1358x over previous
//
#include <hip/hip_runtime.h>

typedef unsigned short ushort_t;
typedef __attribute__((ext_vector_type(8)))  short  short8;
typedef __attribute__((ext_vector_type(4)))  short  short4v;
typedef __attribute__((ext_vector_type(4)))  float  float4v;

#define N_NODES 4096
#define NHEADS  4
#define DK      128
#define ODIM    512
#define KDIM    512

__device__ __forceinline__ float bf2f(ushort_t u) {
    return __uint_as_float(((unsigned)u) << 16);
}
__device__ __forceinline__ ushort_t f2bf_rne(float f) {
    unsigned u = __float_as_uint(f);
    u += 0x7fffu + ((u >> 16) & 1u);
    return (ushort_t)(u >> 16);
}

// ---------------------------------------------------------------------------
// Kernel 1: bit-pack mask = (A != 0) || (i == j); block 0 wave 0 also runs the
// input-dtype detector (1 = fp32 inputs).
// ---------------------------------------------------------------------------
__global__ __launch_bounds__(256) void pack_mask_k(const int* __restrict__ A,
                                                   unsigned long long* __restrict__ P,
                                                   const ushort_t* __restrict__ Hraw,
                                                   int* __restrict__ flag)
{
    if (blockIdx.x == 0 && threadIdx.x < 64) {
        const int lane = threadIdx.x;
        int cnt = 0;
        #pragma unroll
        for (int s = 0; s < 16; ++s) {
            ushort_t v = Hraw[(lane * 16 + s) * 2];
            int e = (v >> 7) & 0xFF;
            cnt += (((e >= 90) && (e <= 140)) || (v == 0)) ? 1 : 0;
        }
        #pragma unroll
        for (int off = 32; off; off >>= 1) cnt += __shfl_down(cnt, off);
        if (lane == 0) *flag = (cnt < 768) ? 1 : 0;
    }
    #pragma unroll
    for (int k = 0; k < 4; ++k) {
        int flat = (k * 16384 + blockIdx.x) * 256 + threadIdx.x;
        int row  = flat >> 12;
        int col  = flat & 4095;
        int a    = A[flat];
        unsigned long long m = __ballot((a != 0) || (row == col));
        if ((threadIdx.x & 63) == 0) P[flat >> 6] = m;
    }
}

// ---------------------------------------------------------------------------
// Kernel 2: WT[n][k] = W[k][n] as bf16 (dual-dtype input).
// ---------------------------------------------------------------------------
__global__ __launch_bounds__(256) void transpose_w_k(const void* __restrict__ W,
                                                     ushort_t* __restrict__ WT,
                                                     const int* __restrict__ flag)
{
    __shared__ ushort_t lt[64][72];
    const int f32 = *flag;
    const int tid = threadIdx.x;
    const int ti = blockIdx.x >> 3, tj = blockIdx.x & 7;
    const int r = tid >> 2, c2 = tid & 3;
    const size_t eo = (size_t)(ti * 64 + r) * KDIM + tj * 64 + c2 * 16;
    if (f32) {
        const float4v* src = (const float4v*)((const float*)W + eo);
        float4v f0 = src[0], f1 = src[1], f2 = src[2], f3 = src[3];
        #pragma unroll
        for (int e = 0; e < 4; ++e) {
            lt[r][c2 * 16 +  0 + e] = f2bf_rne(f0[e]);
            lt[r][c2 * 16 +  4 + e] = f2bf_rne(f1[e]);
            lt[r][c2 * 16 +  8 + e] = f2bf_rne(f2[e]);
            lt[r][c2 * 16 + 12 + e] = f2bf_rne(f3[e]);
        }
    } else {
        const short8* src = (const short8*)((const ushort_t*)W + eo);
        short8 v0 = src[0];
        short8 v1 = src[1];
        *(short8*)&lt[r][c2 * 16]     = v0;
        *(short8*)&lt[r][c2 * 16 + 8] = v1;
    }
    __syncthreads();
    #pragma unroll
    for (int itr = 0; itr < 2; ++itr) {
        int idx = itr * 256 + tid;
        int n = idx >> 3, c = idx & 7;
        short8 vv;
        #pragma unroll
        for (int e = 0; e < 8; ++e) vv[e] = (short)lt[c * 8 + e][n];
        *(short8*)(WT + (size_t)(tj * 64 + n) * KDIM + ti * 64 + c * 8) = vv;
    }
}

// ---------------------------------------------------------------------------
// Kernel 3: WhT[n][i] = (H @ W)[i][n].  16x16x32 MFMA, dual-dtype A loads.
// ---------------------------------------------------------------------------
__global__ __launch_bounds__(256) void gemm_wht_dual_k(const void* __restrict__ H,
                                                       const ushort_t* __restrict__ WT,
                                                       ushort_t* __restrict__ WhT,
                                                       const int* __restrict__ flag)
{
    __shared__ ushort_t lt[64][72];
    const int f32 = *flag;
    const int tid  = threadIdx.x;
    const int lane = tid & 63;
    const int wid  = tid >> 6;
    const int quad = lane >> 4;
    const int l15  = lane & 15;
    const int bm = blockIdx.x >> 3, bn = blockIdx.x & 7;
    const int i0 = bm * 64, n0 = bn * 64;

    const size_t aoff = (size_t)(i0 + wid * 16 + l15) * KDIM + quad * 8;
    const short8* bp0 = (const short8*)(WT + (size_t)(n0 +  0 + l15) * KDIM) + quad;
    const short8* bp1 = (const short8*)(WT + (size_t)(n0 + 16 + l15) * KDIM) + quad;
    const short8* bp2 = (const short8*)(WT + (size_t)(n0 + 32 + l15) * KDIM) + quad;
    const short8* bp3 = (const short8*)(WT + (size_t)(n0 + 48 + l15) * KDIM) + quad;

    float4v acc0, acc1, acc2, acc3;
    #pragma unroll
    for (int e = 0; e < 4; ++e) { acc0[e] = 0.f; acc1[e] = 0.f; acc2[e] = 0.f; acc3[e] = 0.f; }

    #pragma unroll 4
    for (int k8 = 0; k8 < 64; k8 += 4) {
        short8 a;
        if (f32) {
            const float4v* fp = (const float4v*)((const float*)H + aoff + (size_t)k8 * 8);
            float4v x0 = fp[0], x1 = fp[1];
            #pragma unroll
            for (int e = 0; e < 4; ++e) {
                a[e]     = (short)f2bf_rne(x0[e]);
                a[4 + e] = (short)f2bf_rne(x1[e]);
            }
        } else {
            a = *(const short8*)((const ushort_t*)H + aoff + (size_t)k8 * 8);
        }
        acc0 = __builtin_amdgcn_mfma_f32_16x16x32_bf16(a, bp0[k8], acc0, 0, 0, 0);
        acc1 = __builtin_amdgcn_mfma_f32_16x16x32_bf16(a, bp1[k8], acc1, 0, 0, 0);
        acc2 = __builtin_amdgcn_mfma_f32_16x16x32_bf16(a, bp2[k8], acc2, 0, 0, 0);
        acc3 = __builtin_amdgcn_mfma_f32_16x16x32_bf16(a, bp3[k8], acc3, 0, 0, 0);
    }

    #pragma unroll
    for (int r = 0; r < 4; ++r) {
        int m = wid * 16 + quad * 4 + r;
        lt[ 0 + l15][m] = f2bf_rne(acc0[r]);
        lt[16 + l15][m] = f2bf_rne(acc1[r]);
        lt[32 + l15][m] = f2bf_rne(acc2[r]);
        lt[48 + l15][m] = f2bf_rne(acc3[r]);
    }
    __syncthreads();
    #pragma unroll
    for (int itr = 0; itr < 2; ++itr) {
        int idx = itr * 256 + tid;
        int n = idx >> 3, c = idx & 7;
        short8 v = *(const short8*)&lt[n][c * 8];
        *(short8*)(WhT + (size_t)(n0 + n) * N_NODES + i0 + c * 8) = v;
    }
}

// ---------------------------------------------------------------------------
// Kernel 4: sl[h][i], sr[h][i] from WhT (bf16) and a_l/a_r (dual-dtype).
// ---------------------------------------------------------------------------
__global__ __launch_bounds__(256) void slsr_k(const ushort_t* __restrict__ WhT,
                                              const void* __restrict__ al,
                                              const void* __restrict__ ar,
                                              float* __restrict__ sl,
                                              float* __restrict__ sr,
                                              const int* __restrict__ flag)
{
    const int f32 = *flag;
    const int b = blockIdx.x;
    const int h = b >> 4;
    const int i = ((b & 15) << 8) + threadIdx.x;
    float asl = 0.f, asr = 0.f;
    #pragma unroll 8
    for (int d = 0; d < DK; ++d) {
        float v  = bf2f(WhT[(size_t)(h * DK + d) * N_NODES + i]);
        float av = f32 ? ((const float*)al)[h * DK + d] : bf2f(((const ushort_t*)al)[h * DK + d]);
        float bv = f32 ? ((const float*)ar)[h * DK + d] : bf2f(((const ushort_t*)ar)[h * DK + d]);
        asl += v * av;
        asr += v * bv;
    }
    sl[h * N_NODES + i] = asl;
    sr[h * N_NODES + i] = asr;
}

// ---------------------------------------------------------------------------
// Kernel 5 v10: R9 structure (best measured) + XOR bank swizzle (R10-verified
// mapping: slot s of row r holds global chunk s^((r>>1)&3) -> 2-way = free)
// + C1-prescaled sr/sl (exp2(C1*max(x,0.2x)), one less mul per element).
// Grid 1024 = (128 i-tiles x 4 heads x 2 j-halves); 256 thr / 4 waves; wave =
// j-quarter of the half (512 j, 16 windows of 32).  V window staged via 8x
// global_load_lds width-16, double-buffered, vmcnt(8) drains.  MFMA-ones
// denominator; fp32 partials + merge_k.
// ---------------------------------------------------------------------------
__global__ __launch_bounds__(256, 2) void attn_split_k(const ushort_t* __restrict__ WhT,
                                                       const unsigned* __restrict__ Apack,
                                                       const float* __restrict__ sl,
                                                       const float* __restrict__ sr,
                                                       float* __restrict__ Npart,
                                                       float* __restrict__ Dpart)
{
    __shared__ char smem[81920] __attribute__((aligned(16)));
    float*    srs  = (float*)smem;                          // 2048 fp32, 8 KB
    unsigned (*mbuf)[64] = (unsigned (*)[64])(smem + 8192); // 32x64, 8 KB
    ushort_t* vbuf = (ushort_t*)(smem + 16384);             // 4 waves x 2 x 4096

    const int tid  = threadIdx.x;
    const int lane = tid & 63;
    const int wq   = tid >> 6;               // j-quarter of the half
    const int quad = lane >> 4;
    const int l15  = lane & 15;
    const int bx   = blockIdx.x;
    const int half = bx & 1;
    const int h    = (bx >> 1) & 3;
    const int i0   = (bx >> 3) << 5;         // 32-row tile
    const int jbase = half << 11;            // 0 or 2048

    const float C1 = 1.44269504f;             // log2(e)

    for (int j = tid; j < 2048; j += 256) srs[j] = sr[h * N_NODES + jbase + j] * C1;
    for (int t = tid; t < 32 * 64; t += 256) {
        int r = t >> 6, c = t & 63;
        mbuf[r][c] = Apack[(size_t)(i0 + r) * 128 + (half << 6) + c];
    }
    const float slv0 = sl[h * N_NODES + i0 + l15] * C1;
    const float slv1 = sl[h * N_NODES + i0 + 16 + l15] * C1;
    __syncthreads();                          // staging done; no more loop barriers

    float4v acc[2][8];
    #pragma unroll
    for (int mg = 0; mg < 2; ++mg)
        #pragma unroll
        for (int nt = 0; nt < 8; ++nt)
            #pragma unroll
            for (int e = 0; e < 4; ++e) acc[mg][nt][e] = 0.f;
    float4v accden0, accden1;
    #pragma unroll
    for (int e = 0; e < 4; ++e) { accden0[e] = 0.f; accden1[e] = 0.f; }

    short8 ones;
    #pragma unroll
    for (int e = 0; e < 8; ++e) ones[e] = (short)0x3F80;   // bf16 1.0

    // DMA: lane L -> rows q*16 + (L>>2); LDS slot L&3; global chunk (L&3)^((L>>3)&3)
    // => row r slot s holds global chunk s^((r>>1)&3).
    const int Lrow = lane >> 2;
    const int gch  = (lane & 3) ^ ((lane >> 3) & 3);
    const ushort_t* gdma = WhT + (size_t)(h * DK + Lrow) * N_NODES + jbase + gch * 8;

    #define DMA_WIN(CUR, JW)                                                           \
        {   ushort_t* ld_ = vbuf + wq * 8192 + (CUR) * 4096;                           \
            const ushort_t* g_ = gdma + (JW);                                          \
            _Pragma("unroll")                                                          \
            for (int q_ = 0; q_ < 8; ++q_)                                             \
                __builtin_amdgcn_global_load_lds(                                      \
                    (const __attribute__((address_space(1))) void*)(g_ + (size_t)q_ * 16 * N_NODES), \
                    (__attribute__((address_space(3))) void*)(ld_ + q_ * 512),         \
                    16, 0, 0);                                                         \
        }

    DMA_WIN(0, wq * 512)
    DMA_WIN(1, wq * 512 + 32)

    const int so = (quad ^ ((l15 >> 1) & 3)) * 8;   // swizzled read slot (2-way, free)

    #pragma unroll 1
    for (int it = 0; it < 16; ++it) {
        const int cur = it & 1;
        const int jl  = wq * 512 + it * 32;   // local j within the half
        const int mc  = jl >> 5;

        const unsigned wa = mbuf[l15][mc];
        const unsigned wb = mbuf[16 + l15][mc];
        const float4v s0 = *(const float4v*)&srs[jl + quad * 8];
        const float4v s1 = *(const float4v*)&srs[jl + quad * 8 + 4];

        short8 pf0, pf1;
        #pragma unroll
        for (int jj = 0; jj < 8; ++jj) {
            float srj = (jj < 4) ? s0[jj] : s1[jj - 4];
            int bit = quad * 8 + jj;
            float x0 = slv0 + srj;                       // already *C1
            float t0 = fmaxf(x0, x0 * 0.2f);
            t0 = ((wa >> bit) & 1u) ? t0 : -1e30f;
            pf0[jj] = (short)(ushort_t)(__float_as_uint(__builtin_amdgcn_exp2f(t0)) >> 16);
            float x1 = slv1 + srj;
            float t1 = fmaxf(x1, x1 * 0.2f);
            t1 = ((wb >> bit) & 1u) ? t1 : -1e30f;
            pf1[jj] = (short)(ushort_t)(__float_as_uint(__builtin_amdgcn_exp2f(t1)) >> 16);
        }

        if (it == 15) { asm volatile("s_waitcnt vmcnt(0)" ::: "memory"); }
        else          { asm volatile("s_waitcnt vmcnt(8)" ::: "memory"); }

        const ushort_t* vB = vbuf + wq * 8192 + cur * 4096;
        #pragma unroll
        for (int nt = 0; nt < 8; ++nt) {
            short8 b = *(const short8*)(vB + (nt * 16 + l15) * 32 + so);
            acc[0][nt] = __builtin_amdgcn_mfma_f32_16x16x32_bf16(pf0, b, acc[0][nt], 0, 0, 0);
            acc[1][nt] = __builtin_amdgcn_mfma_f32_16x16x32_bf16(pf1, b, acc[1][nt], 0, 0, 0);
        }
        accden0 = __builtin_amdgcn_mfma_f32_16x16x32_bf16(pf0, ones, accden0, 0, 0, 0);
        accden1 = __builtin_amdgcn_mfma_f32_16x16x32_bf16(pf1, ones, accden1, 0, 0, 0);

        if (it < 14) DMA_WIN(cur, wq * 512 + (it + 2) * 32)
    }
    #undef DMA_WIN

    // ---- epilogue: overlay red/lsum onto the V region (all DMAs drained) ----
    float* red  = (float*)(smem + 16384);     // 32 x 128 fp32
    float* lsum = (float*)(smem + 32768);     // 4 x 32 fp32
    __syncthreads();

    if (l15 == 0) {
        #pragma unroll
        for (int r = 0; r < 4; ++r) {
            lsum[wq * 32 + quad * 4 + r]      = accden0[r];
            lsum[wq * 32 + 16 + quad * 4 + r] = accden1[r];
        }
    }
    #define RED_WRITE                                                                \
        { _Pragma("unroll")                                                          \
          for (int mg = 0; mg < 2; ++mg)                                             \
            _Pragma("unroll")                                                        \
            for (int nt = 0; nt < 8; ++nt)                                           \
              _Pragma("unroll")                                                      \
              for (int r = 0; r < 4; ++r)                                            \
                red[(mg * 16 + quad * 4 + r) * 128 + nt * 16 + l15] = acc[mg][nt][r]; }
    #define RED_ADD                                                                 \
        { _Pragma("unroll")                                                          \
          for (int mg = 0; mg < 2; ++mg)                                             \
            _Pragma("unroll")                                                        \
            for (int nt = 0; nt < 8; ++nt)                                           \
              _Pragma("unroll")                                                      \
              for (int r = 0; r < 4; ++r)                                            \
                acc[mg][nt][r] += red[(mg * 16 + quad * 4 + r) * 128 + nt * 16 + l15]; }

    if (wq == 1) RED_WRITE
    __syncthreads();
    if (wq == 0) RED_ADD
    __syncthreads();
    if (wq == 3) RED_WRITE
    __syncthreads();
    if (wq == 2) RED_ADD
    __syncthreads();
    if (wq == 2) RED_WRITE
    __syncthreads();
    if (wq == 0) {
        RED_ADD
        float* Np = Npart + (size_t)half * N_NODES * ODIM;
        #pragma unroll
        for (int mg = 0; mg < 2; ++mg)
            #pragma unroll
            for (int nt = 0; nt < 8; ++nt)
                #pragma unroll
                for (int r = 0; r < 4; ++r) {
                    int rowi = mg * 16 + quad * 4 + r;
                    Np[(size_t)(i0 + rowi) * ODIM + h * DK + nt * 16 + l15] = acc[mg][nt][r];
                }
        if (l15 == 0) {
            #pragma unroll
            for (int mg = 0; mg < 2; ++mg)
                #pragma unroll
                for (int r = 0; r < 4; ++r) {
                    int rowi = mg * 16 + quad * 4 + r;
                    float den = lsum[rowi] + lsum[32 + rowi] + lsum[64 + rowi] + lsum[96 + rowi];
                    Dpart[(half * 4 + h) * N_NODES + i0 + rowi] = den;
                }
        }
    }
    #undef RED_WRITE
    #undef RED_ADD
}

// ---------------------------------------------------------------------------
// Kernel 6: merge halves, normalize, elu, store (dual-dtype out).
// ---------------------------------------------------------------------------
__global__ __launch_bounds__(256) void merge_k(const float* __restrict__ Npart,
                                               const float* __restrict__ Dpart,
                                               void* __restrict__ out,
                                               const int* __restrict__ flag)
{
    const int f32 = *flag;
    const size_t e4 = ((size_t)blockIdx.x * 256 + threadIdx.x) * 4;
    const int i = (int)(e4 >> 9);
    const int c = (int)(e4 & 511);
    const int h = c >> 7;
    const float4v n0 = *(const float4v*)(Npart + e4);
    const float4v n1 = *(const float4v*)(Npart + (size_t)N_NODES * ODIM + e4);
    const float den = Dpart[h * N_NODES + i] + Dpart[(4 + h) * N_NODES + i];
    const float rinv = 1.0f / fmaxf(den, 1e-37f);
    const float C1 = 1.44269504f;
    float o[4];
    #pragma unroll
    for (int k = 0; k < 4; ++k) {
        float v = (n0[k] + n1[k]) * rinv;
        float e = __builtin_amdgcn_exp2f(v * C1) - 1.0f;
        o[k] = (v > 0.f) ? v : e;
    }
    if (f32) {
        float4v ov;
        #pragma unroll
        for (int k = 0; k < 4; ++k) ov[k] = o[k];
        *(float4v*)((float*)out + e4) = ov;
    } else {
        short4v ov;
        #pragma unroll
        for (int k = 0; k < 4; ++k) ov[k] = (short)f2bf_rne(o[k]);
        *(short4v*)((ushort_t*)out + e4) = ov;
    }
}

// ---------------------------------------------------------------------------
// Fallback single-pass attention (R5 structure) if ws too small for partials.
// ---------------------------------------------------------------------------
__global__ __launch_bounds__(256, 2) void attn_single_k(const ushort_t* __restrict__ WhT,
                                                        const unsigned* __restrict__ Apack,
                                                        const float* __restrict__ sl,
                                                        const float* __restrict__ sr,
                                                        void* __restrict__ out,
                                                        const int* __restrict__ flag)
{
    __shared__ float    srs[N_NODES];
    __shared__ unsigned mbuf[32][128];
    __shared__ float    red[2][32][128];
    __shared__ float    lsum[4][32];

    const int f32  = *flag;
    const int tid  = threadIdx.x;
    const int lane = tid & 63;
    const int wq   = tid >> 6;
    const int quad = lane >> 4;
    const int l15  = lane & 15;
    const int h    = blockIdx.x & 3;
    const int i0   = (blockIdx.x >> 2) << 5;

    for (int j = tid; j < N_NODES; j += 256) srs[j] = sr[h * N_NODES + j];
    for (int t = tid; t < 32 * 128; t += 256) {
        int r = t >> 7, c = t & 127;
        mbuf[r][c] = Apack[(size_t)(i0 + r) * 128 + c];
    }
    const float slv0 = sl[h * N_NODES + i0 + l15];
    const float slv1 = sl[h * N_NODES + i0 + 16 + l15];
    __syncthreads();

    const float C1 = 1.44269504f;
    const float C2 = 0.2f * 1.44269504f;

    float4v acc[2][8];
    #pragma unroll
    for (int mg = 0; mg < 2; ++mg)
        #pragma unroll
        for (int nt = 0; nt < 8; ++nt)
            #pragma unroll
            for (int e = 0; e < 4; ++e) acc[mg][nt][e] = 0.f;
    float lacc0 = 0.f, lacc1 = 0.f;

    const ushort_t* vb = WhT + (size_t)(h * DK + l15) * N_NODES + wq * 1024 + quad * 8;

    #pragma unroll 1
    for (int it = 0; it < 16; ++it) {
        const int jl = it * 64;
        const int j0 = wq * 1024 + jl;
        const int mc = j0 >> 5;

        short8 bf[8][2];
        #pragma unroll
        for (int nt = 0; nt < 8; ++nt) {
            bf[nt][0] = *(const short8*)(vb + (size_t)nt * 16 * N_NODES + jl);
            bf[nt][1] = *(const short8*)(vb + (size_t)nt * 16 * N_NODES + jl + 32);
        }

        const unsigned wa0 = mbuf[l15][mc],      wa1 = mbuf[l15][mc + 1];
        const unsigned wb0 = mbuf[16 + l15][mc], wb1 = mbuf[16 + l15][mc + 1];

        short8 pf0[2], pf1[2];
        #pragma unroll
        for (int s = 0; s < 2; ++s) {
            const float* sp = &srs[j0 + s * 32 + quad * 8];
            const float4v s0 = *(const float4v*)sp;
            const float4v s1 = *(const float4v*)(sp + 4);
            const unsigned wa = s ? wa1 : wa0;
            const unsigned wb = s ? wb1 : wb0;
            #pragma unroll
            for (int jj = 0; jj < 8; ++jj) {
                float srj = (jj < 4) ? s0[jj] : s1[jj - 4];
                int bit = quad * 8 + jj;
                float x0 = slv0 + srj;
                float t0 = fmaxf(x0 * C1, x0 * C2);
                t0 = ((wa >> bit) & 1u) ? t0 : -1e30f;
                float p0 = __builtin_amdgcn_exp2f(t0);
                ushort_t h0 = (ushort_t)(__float_as_uint(p0) >> 16);
                lacc0 += bf2f(h0);
                pf0[s][jj] = (short)h0;
                float x1 = slv1 + srj;
                float t1 = fmaxf(x1 * C1, x1 * C2);
                t1 = ((wb >> bit) & 1u) ? t1 : -1e30f;
                float p1 = __builtin_amdgcn_exp2f(t1);
                ushort_t h1 = (ushort_t)(__float_as_uint(p1) >> 16);
                lacc1 += bf2f(h1);
                pf1[s][jj] = (short)h1;
            }
        }

        #pragma unroll
        for (int nt = 0; nt < 8; ++nt) {
            acc[0][nt] = __builtin_amdgcn_mfma_f32_16x16x32_bf16(pf0[0], bf[nt][0], acc[0][nt], 0, 0, 0);
            acc[0][nt] = __builtin_amdgcn_mfma_f32_16x16x32_bf16(pf0[1], bf[nt][1], acc[0][nt], 0, 0, 0);
            acc[1][nt] = __builtin_amdgcn_mfma_f32_16x16x32_bf16(pf1[0], bf[nt][0], acc[1][nt], 0, 0, 0);
            acc[1][nt] = __builtin_amdgcn_mfma_f32_16x16x32_bf16(pf1[1], bf[nt][1], acc[1][nt], 0, 0, 0);
        }
    }

    lacc0 += __shfl_xor(lacc0, 16);
    lacc0 += __shfl_xor(lacc0, 32);
    lacc1 += __shfl_xor(lacc1, 16);
    lacc1 += __shfl_xor(lacc1, 32);
    if (lane < 16) {
        lsum[wq][l15]      = lacc0;
        lsum[wq][16 + l15] = lacc1;
    }
    if (wq >= 2) {
        #pragma unroll
        for (int mg = 0; mg < 2; ++mg)
            #pragma unroll
            for (int nt = 0; nt < 8; ++nt)
                #pragma unroll
                for (int r = 0; r < 4; ++r)
                    red[wq - 2][mg * 16 + quad * 4 + r][nt * 16 + l15] = acc[mg][nt][r];
    }
    __syncthreads();
    if (wq < 2) {
        #pragma unroll
        for (int mg = 0; mg < 2; ++mg)
            #pragma unroll
            for (int nt = 0; nt < 8; ++nt)
                #pragma unroll
                for (int r = 0; r < 4; ++r)
                    acc[mg][nt][r] += red[wq][mg * 16 + quad * 4 + r][nt * 16 + l15];
    }
    __syncthreads();
    if (wq == 1) {
        #pragma unroll
        for (int mg = 0; mg < 2; ++mg)
            #pragma unroll
            for (int nt = 0; nt < 8; ++nt)
                #pragma unroll
                for (int r = 0; r < 4; ++r)
                    red[0][mg * 16 + quad * 4 + r][nt * 16 + l15] = acc[mg][nt][r];
    }
    __syncthreads();
    if (wq == 0) {
        #pragma unroll
        for (int mg = 0; mg < 2; ++mg) {
            float linv[4];
            #pragma unroll
            for (int r = 0; r < 4; ++r) {
                int rowi = mg * 16 + quad * 4 + r;
                float den = lsum[0][rowi] + lsum[1][rowi] + lsum[2][rowi] + lsum[3][rowi];
                linv[r] = 1.0f / fmaxf(den, 1e-37f);
            }
            #pragma unroll
            for (int nt = 0; nt < 8; ++nt)
                #pragma unroll
                for (int r = 0; r < 4; ++r) {
                    int rowi = mg * 16 + quad * 4 + r;
                    float v = (acc[mg][nt][r] + red[0][rowi][nt * 16 + l15]) * linv[r];
                    float e = __builtin_amdgcn_exp2f(v * C1) - 1.0f;
                    float o = (v > 0.f) ? v : e;
                    size_t oidx = (size_t)(i0 + rowi) * ODIM + h * DK + nt * 16 + l15;
                    if (f32) ((float*)out)[oidx] = o;
                    else     ((ushort_t*)out)[oidx] = f2bf_rne(o);
                }
        }
    }
}

// ---------------------------------------------------------------------------
extern "C" void kernel_launch(void* const* d_in, const int* in_sizes, int n_in,
                              void* d_out, int out_size, void* d_ws, size_t ws_size,
                              hipStream_t stream)
{
    const void* H  = d_in[0];
    const int*  A  = (const int*)d_in[1];
    const void* W  = d_in[2];
    const void* al = d_in[3];
    const void* ar = d_in[4];

    if (ws_size < (7u << 20)) return;

    char* ws = (char*)d_ws;
    ushort_t* WhT   = (ushort_t*)ws;                                    // 4 MB
    unsigned long long* Apack = (unsigned long long*)(ws + (4u << 20)); // 2 MB
    ushort_t* WT    = (ushort_t*)(ws + (6u << 20));                     // 512 KB
    float*    sl    = (float*)(ws + (6u << 20) + (512u << 10));         // 64 KB
    float*    sr    = (float*)(ws + (6u << 20) + (576u << 10));         // 64 KB
    int*      flag  = (int*)(ws + (6u << 20) + (640u << 10));           // 4 B
    float*    Npart = (float*)(ws + (12u << 20));                       // 16 MB
    float*    Dpart = (float*)(ws + (28u << 20));                       // 128 KB
    const bool have_split = ws_size >= (29u << 20);

    pack_mask_k    <<<16384, 256, 0, stream>>>(A, Apack, (const ushort_t*)H, flag);
    transpose_w_k  <<<64,    256, 0, stream>>>(W, WT, flag);
    gemm_wht_dual_k<<<512,   256, 0, stream>>>(H, WT, WhT, flag);
    slsr_k         <<<64,    256, 0, stream>>>(WhT, al, ar, sl, sr, flag);
    if (have_split) {
        attn_split_k<<<1024, 256, 0, stream>>>(WhT, (const unsigned*)Apack, sl, sr, Npart, Dpart);
        merge_k     <<<2048, 256, 0, stream>>>(Npart, Dpart, (void*)d_out, flag);
    } else {
        attn_single_k<<<512, 256, 0, stream>>>(WhT, (const unsigned*)Apack, sl, sr, (void*)d_out, flag);
    }
}